// Round 2
// baseline (397.764 us; speedup 1.0000x reference)
//
#include <hip/hip_runtime.h>

#define N_NODES 10000
#define N_EDGES 320000
#define DIN 512
#define DHID 512
#define DOUT 256

typedef __bf16 bf16x8 __attribute__((ext_vector_type(8)));
typedef float f32x4 __attribute__((ext_vector_type(4)));
typedef unsigned short ushort_t;
typedef unsigned int uint_t;

__device__ __forceinline__ float b2f(ushort_t u){
    union { uint_t i; float f; } v; v.i = (uint_t)u << 16; return v.f;
}
__device__ __forceinline__ ushort_t f2b(float f){
    union { float f; uint_t i; } v; v.f = f;
    uint_t i = v.i;
    return (ushort_t)((i + 0x7fffu + ((i >> 16) & 1u)) >> 16); // RNE
}

// ---------------- CSR build ----------------

__global__ void k_degree(const int* __restrict__ dst, int* __restrict__ deg){
    int e = blockIdx.x * 256 + threadIdx.x;
    if (e < N_EDGES) atomicAdd(&deg[dst[e]], 1);
}

__global__ void k_scan(const int* __restrict__ deg, int* __restrict__ row_ptr,
                       int* __restrict__ cursor){
    __shared__ int buf[1024];
    __shared__ int carry;
    int t = threadIdx.x;
    if (t == 0){ carry = 0; row_ptr[0] = 0; }
    __syncthreads();
    for (int c = 0; c < 10; ++c){
        int idx = c * 1024 + t;
        int v = (idx < N_NODES) ? deg[idx] : 0;
        buf[t] = v;
        __syncthreads();
        for (int off = 1; off < 1024; off <<= 1){
            int x = (t >= off) ? buf[t - off] : 0;
            __syncthreads();
            buf[t] += x;
            __syncthreads();
        }
        int inc = buf[t] + carry;   // inclusive prefix + carry
        if (idx < N_NODES){
            row_ptr[idx + 1] = inc;
            cursor[idx] = inc - v;  // exclusive prefix = bucket start
        }
        __syncthreads();
        if (t == 1023) carry = inc;
        __syncthreads();
    }
}

__global__ void k_scatter(const int* __restrict__ src, const int* __restrict__ dst,
                          int* __restrict__ cursor, int* __restrict__ srcs){
    int e = blockIdx.x * 256 + threadIdx.x;
    if (e < N_EDGES){
        int p = atomicAdd(&cursor[dst[e]], 1);
        srcs[p] = src[e];
    }
}

// ---------------- weight f32 -> bf16 conversion (once per call) ----------------

struct CvtArgs { const float* s[9]; ushort_t* d[9]; int n[9]; };

__global__ void k_cvt(CvtArgs a){
    int m = blockIdx.y;
    int i = (blockIdx.x * 256 + threadIdx.x) * 8;
    if (i < a.n[m]){
        const float* sp = a.s[m] + i;
        float4 f0 = *(const float4*)sp;
        float4 f1 = *(const float4*)(sp + 4);
        uint4 u;
        u.x = (uint_t)f2b(f0.x) | ((uint_t)f2b(f0.y) << 16);
        u.y = (uint_t)f2b(f0.z) | ((uint_t)f2b(f0.w) << 16);
        u.z = (uint_t)f2b(f1.x) | ((uint_t)f2b(f1.y) << 16);
        u.w = (uint_t)f2b(f1.z) | ((uint_t)f2b(f1.w) << 16);
        *(uint4*)&a.d[m][i] = u;
    }
}

// ---------------- pe = w_pe^T + b_pe (LDS tile transpose, f32 -> bf16) ----------------

__global__ void k_pe(const float* __restrict__ w_pe, const float* __restrict__ b_pe,
                     ushort_t* __restrict__ h0){
    __shared__ float lt[64][68];  // [n_local][i_local], padded
    int t = threadIdx.x;
    int n0 = blockIdx.x * 64, i0 = blockIdx.y * 64;
    int nc = (t & 15) * 4, ir = t >> 4;   // ir 0..15
    #pragma unroll
    for (int p = 0; p < 4; ++p){
        int i_loc = ir + p * 16;
        float4 v = {0.f, 0.f, 0.f, 0.f};
        if (n0 + nc < N_NODES)  // N_NODES % 4 == 0, chunk-level guard OK
            v = *(const float4*)&w_pe[(size_t)(i0 + i_loc) * N_NODES + n0 + nc];
        lt[nc + 0][i_loc] = v.x;
        lt[nc + 1][i_loc] = v.y;
        lt[nc + 2][i_loc] = v.z;
        lt[nc + 3][i_loc] = v.w;
    }
    __syncthreads();
    int ic = t & 7, nr = t >> 3;   // nr 0..31
    #pragma unroll
    for (int p = 0; p < 2; ++p){
        int n_loc = nr + p * 32;
        int n = n0 + n_loc;
        if (n < N_NODES){
            uint4 u;
            uint_t w01 = (uint_t)f2b(lt[n_loc][ic*8+0] + b_pe[i0+ic*8+0])
                       | ((uint_t)f2b(lt[n_loc][ic*8+1] + b_pe[i0+ic*8+1]) << 16);
            uint_t w23 = (uint_t)f2b(lt[n_loc][ic*8+2] + b_pe[i0+ic*8+2])
                       | ((uint_t)f2b(lt[n_loc][ic*8+3] + b_pe[i0+ic*8+3]) << 16);
            uint_t w45 = (uint_t)f2b(lt[n_loc][ic*8+4] + b_pe[i0+ic*8+4])
                       | ((uint_t)f2b(lt[n_loc][ic*8+5] + b_pe[i0+ic*8+5]) << 16);
            uint_t w67 = (uint_t)f2b(lt[n_loc][ic*8+6] + b_pe[i0+ic*8+6])
                       | ((uint_t)f2b(lt[n_loc][ic*8+7] + b_pe[i0+ic*8+7]) << 16);
            u.x = w01; u.y = w23; u.z = w45; u.w = w67;
            *(uint4*)&h0[(size_t)n * DIN + i0 + ic * 8] = u;
        }
    }
}

// ---------------- mean aggregation (CSR, no atomics, bf16 in/out) ----------------

__global__ void k_agg(const ushort_t* __restrict__ X, const int* __restrict__ row_ptr,
                      const int* __restrict__ srcs, ushort_t* __restrict__ out){
    int n = blockIdx.x, t = threadIdx.x;
    int beg = row_ptr[n], end = row_ptr[n + 1];
    float a0 = 0.f, a1 = 0.f;
    for (int j = beg; j < end; ++j){
        int s = srcs[j];
        uint_t v = *(const uint_t*)&X[(size_t)s * 512 + t * 2];
        a0 += b2f((ushort_t)(v & 0xffffu));
        a1 += b2f((ushort_t)(v >> 16));
    }
    float inv = (end > beg) ? 1.f / (float)(end - beg) : 1.f;
    uint_t o = (uint_t)f2b(a0 * inv) | ((uint_t)f2b(a1 * inv) << 16);
    *(uint_t*)&out[(size_t)n * 512 + t * 2] = o;
}

// ---------------- fused SAGE layer ----------------
// Y(f32) = [leaky?](X@Ws^T + Agg@Wn^T + b) + X@Wr^T + rb ; optional bf16 shadow / dual f32

template<int DO, bool ACT, bool DUAL2, bool WRITE_BF>
__global__ __launch_bounds__(256) void k_layer(
    const ushort_t* __restrict__ X, const ushort_t* __restrict__ G,
    const ushort_t* __restrict__ Ws, const ushort_t* __restrict__ Wn,
    const ushort_t* __restrict__ Wr,
    const float* __restrict__ b, const float* __restrict__ rb,
    float* __restrict__ Y, float* __restrict__ Y2, ushort_t* __restrict__ YB)
{
    __shared__ __align__(16) ushort_t sX[64][40], sG[64][40];
    __shared__ __align__(16) ushort_t sWs[64][40], sWn[64][40], sWr[64][40];
    int t = threadIdx.x;
    int m0 = blockIdx.x * 64, n0 = blockIdx.y * 64;
    int lane = t & 63, w = t >> 6;
    int r = t >> 2, c = t & 3;   // staging: row 0..63, 8-elem chunk 0..3
    f32x4 accS[4] = {}, accG[4] = {}, accR[4] = {};

    for (int k0 = 0; k0 < 512; k0 += 32){
        bf16x8 vx = {}, vg = {};
        if (m0 + r < N_NODES){
            vx = *(const bf16x8*)&X[(size_t)(m0 + r) * 512 + k0 + c * 8];
            vg = *(const bf16x8*)&G[(size_t)(m0 + r) * 512 + k0 + c * 8];
        }
        bf16x8 vs = *(const bf16x8*)&Ws[(size_t)(n0 + r) * 512 + k0 + c * 8];
        bf16x8 vn = *(const bf16x8*)&Wn[(size_t)(n0 + r) * 512 + k0 + c * 8];
        bf16x8 vr = *(const bf16x8*)&Wr[(size_t)(n0 + r) * 512 + k0 + c * 8];
        __syncthreads();  // previous iteration's LDS reads done before overwrite
        *(bf16x8*)&sX[r][c * 8]  = vx;
        *(bf16x8*)&sG[r][c * 8]  = vg;
        *(bf16x8*)&sWs[r][c * 8] = vs;
        *(bf16x8*)&sWn[r][c * 8] = vn;
        *(bf16x8*)&sWr[r][c * 8] = vr;
        __syncthreads();

        int ar = w * 16 + (lane & 15);
        int kk = (lane >> 4) * 8;
        bf16x8 ax = *(const bf16x8*)&sX[ar][kk];
        bf16x8 ag = *(const bf16x8*)&sG[ar][kk];
        #pragma unroll
        for (int cf = 0; cf < 4; ++cf){
            int br = cf * 16 + (lane & 15);
            bf16x8 bs  = *(const bf16x8*)&sWs[br][kk];
            bf16x8 bn  = *(const bf16x8*)&sWn[br][kk];
            bf16x8 brr = *(const bf16x8*)&sWr[br][kk];
            accS[cf] = __builtin_amdgcn_mfma_f32_16x16x32_bf16(ax, bs,  accS[cf], 0, 0, 0);
            accG[cf] = __builtin_amdgcn_mfma_f32_16x16x32_bf16(ag, bn,  accG[cf], 0, 0, 0);
            accR[cf] = __builtin_amdgcn_mfma_f32_16x16x32_bf16(ax, brr, accR[cf], 0, 0, 0);
        }
    }

    // epilogue: C/D layout col = lane&15, row = (lane>>4)*4 + reg
    int col_l = lane & 15;
    int row_l = (lane >> 4) * 4;
    #pragma unroll
    for (int cf = 0; cf < 4; ++cf){
        int col = n0 + cf * 16 + col_l;
        float bb = b[col], rbb = rb[col];
        #pragma unroll
        for (int j = 0; j < 4; ++j){
            int row = m0 + w * 16 + row_l + j;
            if (row < N_NODES){
                float v = accS[cf][j] + accG[cf][j] + bb;
                if (ACT) v = (v > 0.f) ? v : 0.01f * v;
                v += accR[cf][j] + rbb;
                Y[(size_t)row * DO + col] = v;
                if (DUAL2) Y2[(size_t)row * DO + col] = v;
                if (WRITE_BF) YB[(size_t)row * DO + col] = f2b(v);
            }
        }
    }
}

// ---------------- launch ----------------

extern "C" void kernel_launch(void* const* d_in, const int* in_sizes, int n_in,
                              void* d_out, int out_size, void* d_ws, size_t ws_size,
                              hipStream_t stream) {
    const int* edge  = (const int*)d_in[0];
    const int* e_src = edge;
    const int* e_dst = edge + N_EDGES;
    const float* w_pe = (const float*)d_in[1];
    const float* b_pe = (const float*)d_in[2];
    const float* ws0 = (const float*)d_in[3];
    const float* wn0 = (const float*)d_in[4];
    const float* b0  = (const float*)d_in[5];
    const float* wr0 = (const float*)d_in[6];
    const float* rb0 = (const float*)d_in[7];
    const float* ws1 = (const float*)d_in[8];
    const float* wn1 = (const float*)d_in[9];
    const float* b1  = (const float*)d_in[10];
    const float* wr1 = (const float*)d_in[11];
    const float* rb1 = (const float*)d_in[12];
    const float* ws2 = (const float*)d_in[13];
    const float* wn2 = (const float*)d_in[14];
    const float* b2  = (const float*)d_in[15];
    const float* wr2 = (const float*)d_in[16];
    const float* rb2 = (const float*)d_in[17];

    char* wsb = (char*)d_ws;
    ushort_t* h0   = (ushort_t*)wsb;                       // 10,240,000 B
    ushort_t* hb   = (ushort_t*)(wsb + 10240000);          // 10,240,000 B
    ushort_t* aggb = (ushort_t*)(wsb + 20480000);          // 10,240,000 B
    ushort_t* wbf  = (ushort_t*)(wsb + 30720000);          // 1,966,080 elems = 3,932,160 B
    int* deg     = (int*)(wsb + 34652160);                 // 10016 ints
    int* row_ptr = deg + 10016;
    int* cursor  = row_ptr + 10016;
    int* srcs    = cursor + 10016;                         // 320000 ints

    ushort_t* wbf0s = wbf;
    ushort_t* wbf0n = wbf + 262144;
    ushort_t* wbf0r = wbf + 524288;
    ushort_t* wbf1s = wbf + 786432;
    ushort_t* wbf1n = wbf + 1048576;
    ushort_t* wbf1r = wbf + 1310720;
    ushort_t* wbf2s = wbf + 1572864;
    ushort_t* wbf2n = wbf + 1703936;
    ushort_t* wbf2r = wbf + 1835008;

    float* out  = (float*)d_out;
    float* fin  = out;               // [10000][256]
    float* mid0 = out + 2560000;     // [10000][512]
    float* mid1 = out + 7680000;     // [10000][512]
    float* mid2 = out + 12800000;    // [10000][256]

    hipMemsetAsync(deg, 0, 10016 * sizeof(int), stream);
    k_degree <<<1250, 256, 0, stream>>>(e_dst, deg);
    k_scan   <<<1, 1024, 0, stream>>>(deg, row_ptr, cursor);
    k_scatter<<<1250, 256, 0, stream>>>(e_src, e_dst, cursor, srcs);

    CvtArgs ca;
    ca.s[0]=ws0; ca.s[1]=wn0; ca.s[2]=wr0;
    ca.s[3]=ws1; ca.s[4]=wn1; ca.s[5]=wr1;
    ca.s[6]=ws2; ca.s[7]=wn2; ca.s[8]=wr2;
    ca.d[0]=wbf0s; ca.d[1]=wbf0n; ca.d[2]=wbf0r;
    ca.d[3]=wbf1s; ca.d[4]=wbf1n; ca.d[5]=wbf1r;
    ca.d[6]=wbf2s; ca.d[7]=wbf2n; ca.d[8]=wbf2r;
    for (int i = 0; i < 6; ++i) ca.n[i] = 262144;
    for (int i = 6; i < 9; ++i) ca.n[i] = 131072;
    k_cvt<<<dim3(128, 9), 256, 0, stream>>>(ca);

    k_pe<<<dim3(157, 8), 256, 0, stream>>>(w_pe, b_pe, h0);

    k_agg<<<N_NODES, 256, 0, stream>>>(h0, row_ptr, srcs, aggb);
    k_layer<512, true,  false, true ><<<dim3(157, 8), 256, 0, stream>>>(
        h0, aggb, wbf0s, wbf0n, wbf0r, b0, rb0, mid0, nullptr, hb);

    k_agg<<<N_NODES, 256, 0, stream>>>(hb, row_ptr, srcs, aggb);
    k_layer<512, true,  false, true ><<<dim3(157, 8), 256, 0, stream>>>(
        hb, aggb, wbf1s, wbf1n, wbf1r, b1, rb1, mid1, nullptr, h0);

    k_agg<<<N_NODES, 256, 0, stream>>>(h0, row_ptr, srcs, aggb);
    k_layer<256, false, true,  false><<<dim3(157, 4), 256, 0, stream>>>(
        h0, aggb, wbf2s, wbf2n, wbf2r, b2, rb2, mid2, fin, nullptr);
}

// Round 3
// 321.654 us; speedup vs baseline: 1.2366x; 1.2366x over previous
//
#include <hip/hip_runtime.h>

#define N_NODES 10000
#define N_EDGES 320000
#define DIN 512
#define DHID 512
#define DOUT 256

typedef __bf16 bf16x8 __attribute__((ext_vector_type(8)));
typedef float f32x4 __attribute__((ext_vector_type(4)));
typedef unsigned short ushort_t;
typedef unsigned int uint_t;

__device__ __forceinline__ float b2f(ushort_t u){
    union { uint_t i; float f; } v; v.i = (uint_t)u << 16; return v.f;
}
__device__ __forceinline__ ushort_t f2b(float f){
    union { float f; uint_t i; } v; v.f = f;
    uint_t i = v.i;
    return (ushort_t)((i + 0x7fffu + ((i >> 16) & 1u)) >> 16); // RNE
}

// ---------------- CSR build ----------------

__global__ void k_degree(const int* __restrict__ dst, int* __restrict__ deg){
    int e = blockIdx.x * 256 + threadIdx.x;
    if (e < N_EDGES) atomicAdd(&deg[dst[e]], 1);
}

__global__ void k_scan(const int* __restrict__ deg, int* __restrict__ row_ptr,
                       int* __restrict__ cursor){
    __shared__ int buf[1024];
    __shared__ int carry;
    int t = threadIdx.x;
    if (t == 0){ carry = 0; row_ptr[0] = 0; }
    __syncthreads();
    for (int c = 0; c < 10; ++c){
        int idx = c * 1024 + t;
        int v = (idx < N_NODES) ? deg[idx] : 0;
        buf[t] = v;
        __syncthreads();
        for (int off = 1; off < 1024; off <<= 1){
            int x = (t >= off) ? buf[t - off] : 0;
            __syncthreads();
            buf[t] += x;
            __syncthreads();
        }
        int inc = buf[t] + carry;   // inclusive prefix + carry
        if (idx < N_NODES){
            row_ptr[idx + 1] = inc;
            cursor[idx] = inc - v;  // exclusive prefix = bucket start
        }
        __syncthreads();
        if (t == 1023) carry = inc;
        __syncthreads();
    }
}

__global__ void k_scatter(const int* __restrict__ src, const int* __restrict__ dst,
                          int* __restrict__ cursor, int* __restrict__ srcs){
    int e = blockIdx.x * 256 + threadIdx.x;
    if (e < N_EDGES){
        int p = atomicAdd(&cursor[dst[e]], 1);
        srcs[p] = src[e];
    }
}

// ---------------- weight f32 -> bf16 conversion (once per call) ----------------

struct CvtArgs { const float* s[9]; ushort_t* d[9]; int n[9]; };

__global__ void k_cvt(CvtArgs a){
    int m = blockIdx.y;
    int i = (blockIdx.x * 256 + threadIdx.x) * 8;
    if (i < a.n[m]){
        const float* sp = a.s[m] + i;
        float4 f0 = *(const float4*)sp;
        float4 f1 = *(const float4*)(sp + 4);
        uint4 u;
        u.x = (uint_t)f2b(f0.x) | ((uint_t)f2b(f0.y) << 16);
        u.y = (uint_t)f2b(f0.z) | ((uint_t)f2b(f0.w) << 16);
        u.z = (uint_t)f2b(f1.x) | ((uint_t)f2b(f1.y) << 16);
        u.w = (uint_t)f2b(f1.z) | ((uint_t)f2b(f1.w) << 16);
        *(uint4*)&a.d[m][i] = u;
    }
}

// ---------------- pe = w_pe^T + b_pe (LDS tile transpose, f32 -> bf16) ----------------

__global__ void k_pe(const float* __restrict__ w_pe, const float* __restrict__ b_pe,
                     ushort_t* __restrict__ h0){
    __shared__ float lt[64][68];  // [n_local][i_local], padded
    int t = threadIdx.x;
    int n0 = blockIdx.x * 64, i0 = blockIdx.y * 64;
    int nc = (t & 15) * 4, ir = t >> 4;   // ir 0..15
    #pragma unroll
    for (int p = 0; p < 4; ++p){
        int i_loc = ir + p * 16;
        float4 v = {0.f, 0.f, 0.f, 0.f};
        if (n0 + nc < N_NODES)  // N_NODES % 4 == 0, chunk-level guard OK
            v = *(const float4*)&w_pe[(size_t)(i0 + i_loc) * N_NODES + n0 + nc];
        lt[nc + 0][i_loc] = v.x;
        lt[nc + 1][i_loc] = v.y;
        lt[nc + 2][i_loc] = v.z;
        lt[nc + 3][i_loc] = v.w;
    }
    __syncthreads();
    int ic = t & 7, nr = t >> 3;   // nr 0..31
    #pragma unroll
    for (int p = 0; p < 2; ++p){
        int n_loc = nr + p * 32;
        int n = n0 + n_loc;
        if (n < N_NODES){
            uint4 u;
            uint_t w01 = (uint_t)f2b(lt[n_loc][ic*8+0] + b_pe[i0+ic*8+0])
                       | ((uint_t)f2b(lt[n_loc][ic*8+1] + b_pe[i0+ic*8+1]) << 16);
            uint_t w23 = (uint_t)f2b(lt[n_loc][ic*8+2] + b_pe[i0+ic*8+2])
                       | ((uint_t)f2b(lt[n_loc][ic*8+3] + b_pe[i0+ic*8+3]) << 16);
            uint_t w45 = (uint_t)f2b(lt[n_loc][ic*8+4] + b_pe[i0+ic*8+4])
                       | ((uint_t)f2b(lt[n_loc][ic*8+5] + b_pe[i0+ic*8+5]) << 16);
            uint_t w67 = (uint_t)f2b(lt[n_loc][ic*8+6] + b_pe[i0+ic*8+6])
                       | ((uint_t)f2b(lt[n_loc][ic*8+7] + b_pe[i0+ic*8+7]) << 16);
            u.x = w01; u.y = w23; u.z = w45; u.w = w67;
            *(uint4*)&h0[(size_t)n * DIN + i0 + ic * 8] = u;
        }
    }
}

// ---------------- mean aggregation, panel-split for per-XCD L2 residency ----------------
// grid (2500, 4): blockIdx.y = 128-dim panel (slow-varying -> co-resident blocks share
// a 2.56MB panel working set < 4MB per-XCD L2). 4 waves/block, wave = one node.
// Lane reads 4B (2 bf16) at column p*128 + lane*2; 64 lanes = 256B contiguous per row.

__global__ __launch_bounds__(256) void k_agg(
    const ushort_t* __restrict__ X, const int* __restrict__ row_ptr,
    const int* __restrict__ srcs, ushort_t* __restrict__ out)
{
    int w = threadIdx.x >> 6, lane = threadIdx.x & 63;
    int n = blockIdx.x * 4 + w;
    int col = blockIdx.y * 128 + lane * 2;
    int beg = row_ptr[n], end = row_ptr[n + 1];
    float a0 = 0.f, a1 = 0.f;
    int j = beg;
    for (; j + 4 <= end; j += 4){
        int s0 = srcs[j + 0], s1 = srcs[j + 1], s2 = srcs[j + 2], s3 = srcs[j + 3];
        uint_t v0 = *(const uint_t*)&X[(size_t)s0 * 512 + col];
        uint_t v1 = *(const uint_t*)&X[(size_t)s1 * 512 + col];
        uint_t v2 = *(const uint_t*)&X[(size_t)s2 * 512 + col];
        uint_t v3 = *(const uint_t*)&X[(size_t)s3 * 512 + col];
        a0 += b2f((ushort_t)(v0 & 0xffffu)); a1 += b2f((ushort_t)(v0 >> 16));
        a0 += b2f((ushort_t)(v1 & 0xffffu)); a1 += b2f((ushort_t)(v1 >> 16));
        a0 += b2f((ushort_t)(v2 & 0xffffu)); a1 += b2f((ushort_t)(v2 >> 16));
        a0 += b2f((ushort_t)(v3 & 0xffffu)); a1 += b2f((ushort_t)(v3 >> 16));
    }
    for (; j < end; ++j){
        int s = srcs[j];
        uint_t v = *(const uint_t*)&X[(size_t)s * 512 + col];
        a0 += b2f((ushort_t)(v & 0xffffu)); a1 += b2f((ushort_t)(v >> 16));
    }
    float inv = (end > beg) ? 1.f / (float)(end - beg) : 1.f;
    uint_t o = (uint_t)f2b(a0 * inv) | ((uint_t)f2b(a1 * inv) << 16);
    *(uint_t*)&out[(size_t)n * 512 + col] = o;
}

// ---------------- fused SAGE layer ----------------
// Y(f32) = [leaky?](X@Ws^T + Agg@Wn^T + b) + X@Wr^T + rb ; optional bf16 shadow / dual f32

template<int DO, bool ACT, bool DUAL2, bool WRITE_BF>
__global__ __launch_bounds__(256) void k_layer(
    const ushort_t* __restrict__ X, const ushort_t* __restrict__ G,
    const ushort_t* __restrict__ Ws, const ushort_t* __restrict__ Wn,
    const ushort_t* __restrict__ Wr,
    const float* __restrict__ b, const float* __restrict__ rb,
    float* __restrict__ Y, float* __restrict__ Y2, ushort_t* __restrict__ YB)
{
    __shared__ __align__(16) ushort_t sX[64][40], sG[64][40];
    __shared__ __align__(16) ushort_t sWs[64][40], sWn[64][40], sWr[64][40];
    int t = threadIdx.x;
    int m0 = blockIdx.x * 64, n0 = blockIdx.y * 64;
    int lane = t & 63, w = t >> 6;
    int r = t >> 2, c = t & 3;   // staging: row 0..63, 8-elem chunk 0..3
    f32x4 accS[4] = {}, accG[4] = {}, accR[4] = {};

    for (int k0 = 0; k0 < 512; k0 += 32){
        bf16x8 vx = {}, vg = {};
        if (m0 + r < N_NODES){
            vx = *(const bf16x8*)&X[(size_t)(m0 + r) * 512 + k0 + c * 8];
            vg = *(const bf16x8*)&G[(size_t)(m0 + r) * 512 + k0 + c * 8];
        }
        bf16x8 vs = *(const bf16x8*)&Ws[(size_t)(n0 + r) * 512 + k0 + c * 8];
        bf16x8 vn = *(const bf16x8*)&Wn[(size_t)(n0 + r) * 512 + k0 + c * 8];
        bf16x8 vr = *(const bf16x8*)&Wr[(size_t)(n0 + r) * 512 + k0 + c * 8];
        __syncthreads();  // previous iteration's LDS reads done before overwrite
        *(bf16x8*)&sX[r][c * 8]  = vx;
        *(bf16x8*)&sG[r][c * 8]  = vg;
        *(bf16x8*)&sWs[r][c * 8] = vs;
        *(bf16x8*)&sWn[r][c * 8] = vn;
        *(bf16x8*)&sWr[r][c * 8] = vr;
        __syncthreads();

        int ar = w * 16 + (lane & 15);
        int kk = (lane >> 4) * 8;
        bf16x8 ax = *(const bf16x8*)&sX[ar][kk];
        bf16x8 ag = *(const bf16x8*)&sG[ar][kk];
        #pragma unroll
        for (int cf = 0; cf < 4; ++cf){
            int br = cf * 16 + (lane & 15);
            bf16x8 bs  = *(const bf16x8*)&sWs[br][kk];
            bf16x8 bn  = *(const bf16x8*)&sWn[br][kk];
            bf16x8 brr = *(const bf16x8*)&sWr[br][kk];
            accS[cf] = __builtin_amdgcn_mfma_f32_16x16x32_bf16(ax, bs,  accS[cf], 0, 0, 0);
            accG[cf] = __builtin_amdgcn_mfma_f32_16x16x32_bf16(ag, bn,  accG[cf], 0, 0, 0);
            accR[cf] = __builtin_amdgcn_mfma_f32_16x16x32_bf16(ax, brr, accR[cf], 0, 0, 0);
        }
    }

    // epilogue: C/D layout col = lane&15, row = (lane>>4)*4 + reg
    int col_l = lane & 15;
    int row_l = (lane >> 4) * 4;
    #pragma unroll
    for (int cf = 0; cf < 4; ++cf){
        int col = n0 + cf * 16 + col_l;
        float bb = b[col], rbb = rb[col];
        #pragma unroll
        for (int j = 0; j < 4; ++j){
            int row = m0 + w * 16 + row_l + j;
            if (row < N_NODES){
                float v = accS[cf][j] + accG[cf][j] + bb;
                if (ACT) v = (v > 0.f) ? v : 0.01f * v;
                v += accR[cf][j] + rbb;
                Y[(size_t)row * DO + col] = v;
                if (DUAL2) Y2[(size_t)row * DO + col] = v;
                if (WRITE_BF) YB[(size_t)row * DO + col] = f2b(v);
            }
        }
    }
}

// ---------------- launch ----------------

extern "C" void kernel_launch(void* const* d_in, const int* in_sizes, int n_in,
                              void* d_out, int out_size, void* d_ws, size_t ws_size,
                              hipStream_t stream) {
    const int* edge  = (const int*)d_in[0];
    const int* e_src = edge;
    const int* e_dst = edge + N_EDGES;
    const float* w_pe = (const float*)d_in[1];
    const float* b_pe = (const float*)d_in[2];
    const float* ws0 = (const float*)d_in[3];
    const float* wn0 = (const float*)d_in[4];
    const float* b0  = (const float*)d_in[5];
    const float* wr0 = (const float*)d_in[6];
    const float* rb0 = (const float*)d_in[7];
    const float* ws1 = (const float*)d_in[8];
    const float* wn1 = (const float*)d_in[9];
    const float* b1  = (const float*)d_in[10];
    const float* wr1 = (const float*)d_in[11];
    const float* rb1 = (const float*)d_in[12];
    const float* ws2 = (const float*)d_in[13];
    const float* wn2 = (const float*)d_in[14];
    const float* b2  = (const float*)d_in[15];
    const float* wr2 = (const float*)d_in[16];
    const float* rb2 = (const float*)d_in[17];

    char* wsb = (char*)d_ws;
    ushort_t* h0   = (ushort_t*)wsb;                       // 10,240,000 B
    ushort_t* hb   = (ushort_t*)(wsb + 10240000);          // 10,240,000 B
    ushort_t* aggb = (ushort_t*)(wsb + 20480000);          // 10,240,000 B
    ushort_t* wbf  = (ushort_t*)(wsb + 30720000);          // 1,966,080 elems = 3,932,160 B
    int* deg     = (int*)(wsb + 34652160);                 // 10016 ints
    int* row_ptr = deg + 10016;
    int* cursor  = row_ptr + 10016;
    int* srcs    = cursor + 10016;                         // 320000 ints

    ushort_t* wbf0s = wbf;
    ushort_t* wbf0n = wbf + 262144;
    ushort_t* wbf0r = wbf + 524288;
    ushort_t* wbf1s = wbf + 786432;
    ushort_t* wbf1n = wbf + 1048576;
    ushort_t* wbf1r = wbf + 1310720;
    ushort_t* wbf2s = wbf + 1572864;
    ushort_t* wbf2n = wbf + 1703936;
    ushort_t* wbf2r = wbf + 1835008;

    float* out  = (float*)d_out;
    float* fin  = out;               // [10000][256]
    float* mid0 = out + 2560000;     // [10000][512]
    float* mid1 = out + 7680000;     // [10000][512]
    float* mid2 = out + 12800000;    // [10000][256]

    hipMemsetAsync(deg, 0, 10016 * sizeof(int), stream);
    k_degree <<<1250, 256, 0, stream>>>(e_dst, deg);
    k_scan   <<<1, 1024, 0, stream>>>(deg, row_ptr, cursor);
    k_scatter<<<1250, 256, 0, stream>>>(e_src, e_dst, cursor, srcs);

    CvtArgs ca;
    ca.s[0]=ws0; ca.s[1]=wn0; ca.s[2]=wr0;
    ca.s[3]=ws1; ca.s[4]=wn1; ca.s[5]=wr1;
    ca.s[6]=ws2; ca.s[7]=wn2; ca.s[8]=wr2;
    ca.d[0]=wbf0s; ca.d[1]=wbf0n; ca.d[2]=wbf0r;
    ca.d[3]=wbf1s; ca.d[4]=wbf1n; ca.d[5]=wbf1r;
    ca.d[6]=wbf2s; ca.d[7]=wbf2n; ca.d[8]=wbf2r;
    for (int i = 0; i < 6; ++i) ca.n[i] = 262144;
    for (int i = 6; i < 9; ++i) ca.n[i] = 131072;
    k_cvt<<<dim3(128, 9), 256, 0, stream>>>(ca);

    k_pe<<<dim3(157, 8), 256, 0, stream>>>(w_pe, b_pe, h0);

    k_agg<<<dim3(2500, 4), 256, 0, stream>>>(h0, row_ptr, srcs, aggb);
    k_layer<512, true,  false, true ><<<dim3(157, 8), 256, 0, stream>>>(
        h0, aggb, wbf0s, wbf0n, wbf0r, b0, rb0, mid0, nullptr, hb);

    k_agg<<<dim3(2500, 4), 256, 0, stream>>>(hb, row_ptr, srcs, aggb);
    k_layer<512, true,  false, true ><<<dim3(157, 8), 256, 0, stream>>>(
        hb, aggb, wbf1s, wbf1n, wbf1r, b1, rb1, mid1, nullptr, h0);

    k_agg<<<dim3(2500, 4), 256, 0, stream>>>(h0, row_ptr, srcs, aggb);
    k_layer<256, false, true,  false><<<dim3(157, 4), 256, 0, stream>>>(
        h0, aggb, wbf2s, wbf2n, wbf2r, b2, rb2, mid2, fin, nullptr);
}